// Round 2
// baseline (170.461 us; speedup 1.0000x reference)
//
#include <hip/hip_runtime.h>

typedef unsigned short u16;
typedef unsigned int u32;
typedef __attribute__((ext_vector_type(8))) short bf16x8;
typedef __attribute__((ext_vector_type(4))) float f32x4;

#define NTOK 4096

__device__ __forceinline__ float b2f(u16 u) {
    u32 v = ((u32)u) << 16;
    return __builtin_bit_cast(float, v);
}
__device__ __forceinline__ u16 f2b(float f) {
    u32 u = __builtin_bit_cast(u32, f);
    u32 r = (u + 0x7fffu + ((u >> 16) & 1u)) >> 16;  // RNE
    return (u16)r;
}
__device__ __forceinline__ u32 pack2(float lo, float hi) {
    return (u32)f2b(lo) | ((u32)f2b(hi) << 16);
}
__device__ __forceinline__ bf16x8 cvt8(const float* __restrict__ p) {
    float4 a = *(const float4*)p;
    float4 b = *(const float4*)(p + 4);
    bf16x8 r;
    r[0] = (short)f2b(a.x); r[1] = (short)f2b(a.y);
    r[2] = (short)f2b(a.z); r[3] = (short)f2b(a.w);
    r[4] = (short)f2b(b.x); r[5] = (short)f2b(b.y);
    r[6] = (short)f2b(b.z); r[7] = (short)f2b(b.w);
    return r;
}

// ---------------------------------------------------------------------------
// Kernel 1: QKV projection. grid (64,4) blocks of 256 threads.
// Per block: 64 tokens of one batch. Stage seg^T/gauss^T (fp32 -> bf16) in
// LDS token-major with XOR-swizzled 8-elem c-blocks; MFMA against W rows
// converted from global fp32. Outputs (bf16 workspace): token-major Qt/Kt/
// Vtok [B,N,64] and channel-major Vchan [B,64,N].
// ---------------------------------------------------------------------------
__global__ __launch_bounds__(256) void qkv_kernel(
    const float* __restrict__ seg, const float* __restrict__ gau,
    const float* __restrict__ Wq, const float* __restrict__ bq,
    const float* __restrict__ Wk, const float* __restrict__ bk,
    const float* __restrict__ Wv, const float* __restrict__ bv,
    u16* __restrict__ Qt, u16* __restrict__ Kt,
    u16* __restrict__ Vtok, u16* __restrict__ Vchan)
{
    __shared__ __align__(16) u16 sSegT[64 * 64];
    __shared__ __align__(16) u16 sGauT[64 * 64];
    const int tid = threadIdx.x;
    const int b = blockIdx.y;
    const int n0 = blockIdx.x * 64;

    // load [c][n] coalesced fp32, store transposed [tok][c] bf16, XOR swizzle
    for (int idx = tid; idx < 4096; idx += 256) {
        int c = idx >> 6, t = idx & 63;
        int sw = t * 64 + ((((c >> 3) ^ (t & 7)) << 3) | (c & 7));
        sSegT[sw] = f2b(seg[(size_t)(b * 64 + c) * NTOK + n0 + t]);
        sGauT[sw] = f2b(gau[(size_t)(b * 64 + c) * NTOK + n0 + t]);
    }
    __syncthreads();

    const int lane = tid & 63;
    const int tb = tid >> 6;          // wave = token-block
    const int q = lane & 15, g = lane >> 4;
    const int tok = tb * 16 + q;      // A-frag row (token)

    bf16x8 as[2], ag[2];
#pragma unroll
    for (int ks = 0; ks < 2; ++ks) {
        int c0 = ks * 32 + g * 8;
        int sw = tok * 64 + (((c0 >> 3) ^ (tok & 7)) << 3);
        as[ks] = *(const bf16x8*)&sSegT[sw];
        ag[ks] = *(const bf16x8*)&sGauT[sw];
    }

    const size_t obase = (size_t)b * NTOK * 64;
    const size_t rowb = (size_t)(n0 + tb * 16 + g * 4);

#pragma unroll
    for (int ob = 0; ob < 4; ++ob) {
        int o = ob * 16 + q;          // B-frag col (out channel)
        // ---- Q ----
        {
            float bias = bq[o];
            f32x4 acc = {bias, bias, bias, bias};
            bf16x8 w0 = cvt8(&Wq[o * 64 + g * 8]);
            bf16x8 w1 = cvt8(&Wq[o * 64 + 32 + g * 8]);
            acc = __builtin_amdgcn_mfma_f32_16x16x32_bf16(as[0], w0, acc, 0, 0, 0);
            acc = __builtin_amdgcn_mfma_f32_16x16x32_bf16(as[1], w1, acc, 0, 0, 0);
#pragma unroll
            for (int j = 0; j < 4; ++j)
                Qt[obase + (rowb + j) * 64 + o] = f2b(acc[j]);
        }
        // ---- K ----
        {
            float bias = bk[o];
            f32x4 acc = {bias, bias, bias, bias};
            bf16x8 w0 = cvt8(&Wk[o * 64 + g * 8]);
            bf16x8 w1 = cvt8(&Wk[o * 64 + 32 + g * 8]);
            acc = __builtin_amdgcn_mfma_f32_16x16x32_bf16(as[0], w0, acc, 0, 0, 0);
            acc = __builtin_amdgcn_mfma_f32_16x16x32_bf16(as[1], w1, acc, 0, 0, 0);
#pragma unroll
            for (int j = 0; j < 4; ++j)
                Kt[obase + (rowb + j) * 64 + o] = f2b(acc[j]);
        }
        // ---- V (from gauss) ----
        {
            float bias = bv[o];
            f32x4 acc = {bias, bias, bias, bias};
            bf16x8 w0 = cvt8(&Wv[o * 64 + g * 8]);
            bf16x8 w1 = cvt8(&Wv[o * 64 + 32 + g * 8]);
            acc = __builtin_amdgcn_mfma_f32_16x16x32_bf16(ag[0], w0, acc, 0, 0, 0);
            acc = __builtin_amdgcn_mfma_f32_16x16x32_bf16(ag[1], w1, acc, 0, 0, 0);
            ushort4 v4;
            v4.x = f2b(acc[0]); v4.y = f2b(acc[1]);
            v4.z = f2b(acc[2]); v4.w = f2b(acc[3]);
#pragma unroll
            for (int j = 0; j < 4; ++j)
                Vtok[obase + (rowb + j) * 64 + o] = f2b(acc[j]);
            *(ushort4*)&Vchan[(size_t)(b * 64 + o) * NTOK + n0 + tb * 16 + g * 4] = v4;
        }
    }
}

// ---------------------------------------------------------------------------
// Kernel 2: flash attention + LN1 + FFN + LN2 + transposed fp32 store.
// grid (64,4), 256 threads = 4 independent waves, each owns 16 queries.
// Swapped QK^T: S^T = mfma(K, Q) so each lane holds 8 scores of one query.
// ---------------------------------------------------------------------------
__global__ __launch_bounds__(256) void attn_kernel(
    const u16* __restrict__ Qt, const u16* __restrict__ Kt,
    const u16* __restrict__ Vtok, const u16* __restrict__ Vchan,
    const float* __restrict__ ln1w, const float* __restrict__ ln1b,
    const float* __restrict__ ln2w, const float* __restrict__ ln2b,
    const float* __restrict__ W1, const float* __restrict__ b1,
    const float* __restrict__ W2, const float* __restrict__ b2,
    float* __restrict__ out)
{
    __shared__ __align__(16) u16 sP[4 * 16 * 32];   // per-wave P tile [q][k]
    __shared__ __align__(16) u16 sX[4 * 16 * 64];   // per-wave FFN tile [q][c]

    const int tid = threadIdx.x;
    const int wv = tid >> 6;
    const int lane = tid & 63;
    const int q = lane & 15, g = lane >> 4;
    const int b = blockIdx.y;
    const int q0 = blockIdx.x * 64 + wv * 16;
    const int n_q = q0 + q;
    const size_t tb_ = (size_t)b * NTOK * 64;

    // Q fragments hoisted (B-operand: col = query q, k = channel)
    bf16x8 qf0 = *(const bf16x8*)&Qt[tb_ + (size_t)n_q * 64 + g * 8];
    bf16x8 qf1 = *(const bf16x8*)&Qt[tb_ + (size_t)n_q * 64 + 32 + g * 8];

    f32x4 zero4 = {0.f, 0.f, 0.f, 0.f};
    f32x4 acc[4];
#pragma unroll
    for (int i = 0; i < 4; ++i) acc[i] = zero4;
    float m = -1e30f, l = 0.f;

    u32* sPu = (u32*)sP;
    const int pwr = wv * 256 + q * 16 + g * 2;          // u32 index for P writes
    const u16* pfp = &sP[wv * 512 + q * 32 + g * 8];    // b128 P read
    const u16* Vbase = &Vchan[(size_t)b * 64 * NTOK + g * 8];

    for (int k0 = 0; k0 < NTOK; k0 += 32) {
        const u16* Kp = &Kt[tb_ + (size_t)k0 * 64];
        bf16x8 kf00 = *(const bf16x8*)&Kp[q * 64 + g * 8];
        bf16x8 kf01 = *(const bf16x8*)&Kp[q * 64 + 32 + g * 8];
        bf16x8 kf10 = *(const bf16x8*)&Kp[(16 + q) * 64 + g * 8];
        bf16x8 kf11 = *(const bf16x8*)&Kp[(16 + q) * 64 + 32 + g * 8];

        f32x4 s0 = __builtin_amdgcn_mfma_f32_16x16x32_bf16(kf00, qf0, zero4, 0, 0, 0);
        s0 = __builtin_amdgcn_mfma_f32_16x16x32_bf16(kf01, qf1, s0, 0, 0, 0);
        f32x4 s1 = __builtin_amdgcn_mfma_f32_16x16x32_bf16(kf10, qf0, zero4, 0, 0, 0);
        s1 = __builtin_amdgcn_mfma_f32_16x16x32_bf16(kf11, qf1, s1, 0, 0, 0);

        // lane holds S[q][k0 + g*4+j] (s0) and S[q][k0+16+g*4+j] (s1)
        float sv[8];
#pragma unroll
        for (int j = 0; j < 4; ++j) { sv[j] = s0[j] * 0.125f; sv[4 + j] = s1[j] * 0.125f; }

        float tm = sv[0];
#pragma unroll
        for (int j = 1; j < 8; ++j) tm = fmaxf(tm, sv[j]);
        tm = fmaxf(tm, __shfl_xor(tm, 16));
        tm = fmaxf(tm, __shfl_xor(tm, 32));

        float mn = fmaxf(m, tm);
        float corr = __expf(m - mn);
        m = mn;

        float p[8];
        float ps = 0.f;
#pragma unroll
        for (int j = 0; j < 8; ++j) { p[j] = __expf(sv[j] - mn); ps += p[j]; }
        ps += __shfl_xor(ps, 16);
        ps += __shfl_xor(ps, 32);
        l = l * corr + ps;
#pragma unroll
        for (int i = 0; i < 4; ++i) acc[i] *= corr;

        // P -> LDS [q][k], bf16
        sPu[pwr + 0] = pack2(p[0], p[1]);
        sPu[pwr + 1] = pack2(p[2], p[3]);
        sPu[pwr + 8] = pack2(p[4], p[5]);
        sPu[pwr + 9] = pack2(p[6], p[7]);
        asm volatile("s_waitcnt lgkmcnt(0)" ::: "memory");
        __builtin_amdgcn_sched_barrier(0);
        bf16x8 pf = *(const bf16x8*)pfp;

        const u16* Vp = Vbase + k0;
#pragma unroll
        for (int cb = 0; cb < 4; ++cb) {
            bf16x8 vf = *(const bf16x8*)&Vp[(size_t)(cb * 16 + q) * NTOK];
            acc[cb] = __builtin_amdgcn_mfma_f32_16x16x32_bf16(vf, pf, acc[cb], 0, 0, 0);
        }
    }

    // ---------------- epilogue: lane owns channels c = cb*16 + g*4 + j of query n_q
    float inv_l = 1.0f / l;
    float x1[4][4];
#pragma unroll
    for (int cb = 0; cb < 4; ++cb) {
        ushort4 vv = *(const ushort4*)&Vtok[tb_ + (size_t)n_q * 64 + cb * 16 + g * 4];
        x1[cb][0] = acc[cb][0] * inv_l + b2f(vv.x);
        x1[cb][1] = acc[cb][1] * inv_l + b2f(vv.y);
        x1[cb][2] = acc[cb][2] * inv_l + b2f(vv.z);
        x1[cb][3] = acc[cb][3] * inv_l + b2f(vv.w);
    }

    // LN1 (lanes q, q+16, q+32, q+48 hold one token's 64 channels)
    float s_ = 0.f;
#pragma unroll
    for (int cb = 0; cb < 4; ++cb)
        for (int j = 0; j < 4; ++j) s_ += x1[cb][j];
    s_ += __shfl_xor(s_, 16); s_ += __shfl_xor(s_, 32);
    float mean = s_ * (1.f / 64.f);
    float v_ = 0.f;
#pragma unroll
    for (int cb = 0; cb < 4; ++cb)
        for (int j = 0; j < 4; ++j) { float d = x1[cb][j] - mean; v_ += d * d; }
    v_ += __shfl_xor(v_, 16); v_ += __shfl_xor(v_, 32);
    float rstd = rsqrtf(v_ * (1.f / 64.f) + 1e-5f);

    float xh[4][4];
#pragma unroll
    for (int cb = 0; cb < 4; ++cb) {
        float4 lw = *(const float4*)&ln1w[cb * 16 + g * 4];
        float4 lb = *(const float4*)&ln1b[cb * 16 + g * 4];
        xh[cb][0] = (x1[cb][0] - mean) * rstd * lw.x + lb.x;
        xh[cb][1] = (x1[cb][1] - mean) * rstd * lw.y + lb.y;
        xh[cb][2] = (x1[cb][2] - mean) * rstd * lw.z + lb.z;
        xh[cb][3] = (x1[cb][3] - mean) * rstd * lw.w + lb.w;
    }

    // FFN layer 1: H^T = W1 * x^T via LDS roundtrip
    u32* sXu = (u32*)sX;
    const int xwr = wv * 512 + q * 32;
#pragma unroll
    for (int cb = 0; cb < 4; ++cb) {
        sXu[xwr + cb * 8 + g * 2 + 0] = pack2(xh[cb][0], xh[cb][1]);
        sXu[xwr + cb * 8 + g * 2 + 1] = pack2(xh[cb][2], xh[cb][3]);
    }
    asm volatile("s_waitcnt lgkmcnt(0)" ::: "memory");
    __builtin_amdgcn_sched_barrier(0);
    const u16* xrp = &sX[wv * 1024 + q * 64 + g * 8];
    bf16x8 xb0 = *(const bf16x8*)&xrp[0];
    bf16x8 xb1 = *(const bf16x8*)&xrp[32];

    float h[4][4];
#pragma unroll
    for (int ob = 0; ob < 4; ++ob) {
        float4 bb = *(const float4*)&b1[ob * 16 + g * 4];
        f32x4 hacc = {bb.x, bb.y, bb.z, bb.w};
        bf16x8 w0 = cvt8(&W1[(size_t)(ob * 16 + q) * 64 + g * 8]);
        bf16x8 w1 = cvt8(&W1[(size_t)(ob * 16 + q) * 64 + 32 + g * 8]);
        hacc = __builtin_amdgcn_mfma_f32_16x16x32_bf16(w0, xb0, hacc, 0, 0, 0);
        hacc = __builtin_amdgcn_mfma_f32_16x16x32_bf16(w1, xb1, hacc, 0, 0, 0);
#pragma unroll
        for (int j = 0; j < 4; ++j) h[ob][j] = fmaxf(hacc[j], 0.f);
    }

    // write relu(h) back to LDS [q][o], read as B-frag for layer 2
#pragma unroll
    for (int ob = 0; ob < 4; ++ob) {
        sXu[xwr + ob * 8 + g * 2 + 0] = pack2(h[ob][0], h[ob][1]);
        sXu[xwr + ob * 8 + g * 2 + 1] = pack2(h[ob][2], h[ob][3]);
    }
    asm volatile("s_waitcnt lgkmcnt(0)" ::: "memory");
    __builtin_amdgcn_sched_barrier(0);
    bf16x8 hb0 = *(const bf16x8*)&xrp[0];
    bf16x8 hb1 = *(const bf16x8*)&xrp[32];

    float f_[4][4];
#pragma unroll
    for (int cb = 0; cb < 4; ++cb) {
        float4 bb = *(const float4*)&b2[cb * 16 + g * 4];
        f32x4 yacc = {bb.x, bb.y, bb.z, bb.w};
        bf16x8 w0 = cvt8(&W2[(size_t)(cb * 16 + q) * 64 + g * 8]);
        bf16x8 w1 = cvt8(&W2[(size_t)(cb * 16 + q) * 64 + 32 + g * 8]);
        yacc = __builtin_amdgcn_mfma_f32_16x16x32_bf16(w0, hb0, yacc, 0, 0, 0);
        yacc = __builtin_amdgcn_mfma_f32_16x16x32_bf16(w1, hb1, yacc, 0, 0, 0);
#pragma unroll
        for (int j = 0; j < 4; ++j) f_[cb][j] = xh[cb][j] + yacc[j];
    }

    // LN2
    float s2 = 0.f;
#pragma unroll
    for (int cb = 0; cb < 4; ++cb)
        for (int j = 0; j < 4; ++j) s2 += f_[cb][j];
    s2 += __shfl_xor(s2, 16); s2 += __shfl_xor(s2, 32);
    float mean2 = s2 * (1.f / 64.f);
    float v2 = 0.f;
#pragma unroll
    for (int cb = 0; cb < 4; ++cb)
        for (int j = 0; j < 4; ++j) { float d = f_[cb][j] - mean2; v2 += d * d; }
    v2 += __shfl_xor(v2, 16); v2 += __shfl_xor(v2, 32);
    float rstd2 = rsqrtf(v2 * (1.f / 64.f) + 1e-5f);

#pragma unroll
    for (int cb = 0; cb < 4; ++cb) {
        float4 lw = *(const float4*)&ln2w[cb * 16 + g * 4];
        float4 lb = *(const float4*)&ln2b[cb * 16 + g * 4];
        float o0 = (f_[cb][0] - mean2) * rstd2 * lw.x + lb.x;
        float o1 = (f_[cb][1] - mean2) * rstd2 * lw.y + lb.y;
        float o2 = (f_[cb][2] - mean2) * rstd2 * lw.z + lb.z;
        float o3 = (f_[cb][3] - mean2) * rstd2 * lw.w + lb.w;
        // out[b][c][n], fp32
        out[(size_t)(b * 64 + cb * 16 + g * 4 + 0) * NTOK + n_q] = o0;
        out[(size_t)(b * 64 + cb * 16 + g * 4 + 1) * NTOK + n_q] = o1;
        out[(size_t)(b * 64 + cb * 16 + g * 4 + 2) * NTOK + n_q] = o2;
        out[(size_t)(b * 64 + cb * 16 + g * 4 + 3) * NTOK + n_q] = o3;
    }
}

extern "C" void kernel_launch(void* const* d_in, const int* in_sizes, int n_in,
                              void* d_out, int out_size, void* d_ws, size_t ws_size,
                              hipStream_t stream) {
    const float* seg = (const float*)d_in[0];
    const float* gau = (const float*)d_in[1];
    const float* Wq = (const float*)d_in[2];
    const float* bq = (const float*)d_in[3];
    const float* Wk = (const float*)d_in[4];
    const float* bk = (const float*)d_in[5];
    const float* Wv = (const float*)d_in[6];
    const float* bv = (const float*)d_in[7];
    const float* ln1w = (const float*)d_in[8];
    const float* ln1b = (const float*)d_in[9];
    const float* ln2w = (const float*)d_in[10];
    const float* ln2b = (const float*)d_in[11];
    const float* W1 = (const float*)d_in[12];
    const float* b1 = (const float*)d_in[13];
    const float* W2 = (const float*)d_in[14];
    const float* b2 = (const float*)d_in[15];

    u16* Qt = (u16*)d_ws;
    u16* Kt = Qt + (size_t)4 * NTOK * 64;
    u16* Vtok = Kt + (size_t)4 * NTOK * 64;
    u16* Vchan = Vtok + (size_t)4 * NTOK * 64;
    float* outp = (float*)d_out;

    dim3 grid(64, 4), blk(256);
    hipLaunchKernelGGL(qkv_kernel, grid, blk, 0, stream,
                       seg, gau, Wq, bq, Wk, bk, Wv, bv, Qt, Kt, Vtok, Vchan);
    hipLaunchKernelGGL(attn_kernel, grid, blk, 0, stream,
                       Qt, Kt, Vtok, Vchan, ln1w, ln1b, ln2w, ln2b,
                       W1, b1, W2, b2, outp);
}